// Round 15
// baseline (109.766 us; speedup 1.0000x reference)
//
#include <hip/hip_runtime.h>

#define MAXP 1048576           // static pair bound (MAX_PAIRS)
#define NATOMS 8192
#define D2_CUT 0x1.8ffffep+4f  // fl(sqrt(s))<5  <=>  s < 25-2^-19
#define CINV 0.175f            // 7/40: 7^3=343 cells, width 5.714 > 5.0004 (conservative)
#define CAP 192                // max hits/row (avg 56; huge safety margin)

// d_ws layout (float offsets); ws is ~256 MB (it's what the harness poisons)
#define W_CELLOFF 0            // 344 ints
#define W_SORTID  512          // 8192 ints
#define W_SORTPOS 16384        // float4[8192]
#define W_ROWCNT  49152        // 8192 ints

__device__ __forceinline__ float sq3_nc(float x, float y, float z) {
#pragma clang fp contract(off)
  float a = x * x;
  float b = y * y;
  float c = z * z;
  return (a + b) + c;
}

// mask per _pairwise_dist: sq_i + sq_j - 2*(x @ x.T); BLAS K=3 FMA chain (bit-exact r12-r14)
__device__ __forceinline__ float d2_gram(float xi, float yi, float zi, float sqi,
                                         float xj, float yj, float zj, float sqj) {
#pragma clang fp contract(off)
  float g = xi * xj;
  g = __builtin_fmaf(yi, yj, g);
  g = __builtin_fmaf(zi, zj, g);
  float t = sqi + sqj;
  float d2 = t - 2.0f * g;
  return d2;
}

__device__ __forceinline__ float d2_direct(float xi, float yi, float zi,
                                           float xj, float yj, float zj) {
#pragma clang fp contract(off)
  float dx = xj - xi;
  float dy = yj - yi;
  float dz = zj - zi;
  float a = dx * dx;
  float b = dy * dy;
  float c = dz * dz;
  return (a + b) + c;
}

__device__ __forceinline__ int cellco(float v) {
  int c = (int)(v * CINV);
  return c < 0 ? 0 : (c > 6 ? 6 : c);
}

// K1: single block does bin + scan + scatter entirely in LDS
__global__ __launch_bounds__(1024) void nl_bin(const float* __restrict__ pos,
                                               float* __restrict__ ws) {
  __shared__ int hcnt[343];
  __shared__ int hoff[344];
  __shared__ int hcur[343];
  __shared__ int s[512];
  const int tid = threadIdx.x;
  if (tid < 343) { hcnt[tid] = 0; hcur[tid] = 0; }
  __syncthreads();

  float x[8], y[8], z[8];
  int cl[8];
#pragma unroll
  for (int k = 0; k < 8; ++k) {
    int a = tid + k * 1024;
    x[k] = pos[3 * a]; y[k] = pos[3 * a + 1]; z[k] = pos[3 * a + 2];
    cl[k] = cellco(x[k]) + 7 * cellco(y[k]) + 49 * cellco(z[k]);
    atomicAdd(&hcnt[cl[k]], 1);
  }
  __syncthreads();

  if (tid < 512) s[tid] = (tid < 343) ? hcnt[tid] : 0;
  __syncthreads();
  for (int off = 1; off < 512; off <<= 1) {
    int v = (tid < 512 && tid >= off) ? s[tid - off] : 0;
    __syncthreads();
    if (tid < 512) s[tid] += v;
    __syncthreads();
  }
  if (tid < 343) hoff[tid] = (tid == 0) ? 0 : s[tid - 1];
  if (tid == 343) hoff[343] = NATOMS;
  __syncthreads();
  if (tid < 344) ((int*)(ws + W_CELLOFF))[tid] = hoff[tid];

  int* sortid = (int*)(ws + W_SORTID);
  float4* sortpos = (float4*)(ws + W_SORTPOS);
#pragma unroll
  for (int k = 0; k < 8; ++k) {
    int slot = hoff[cl[k]] + atomicAdd(&hcur[cl[k]], 1);
    sortid[slot] = tid + k * 1024;
    sortpos[slot] = make_float4(x[k], y[k], z[k], sq3_nc(x[k], y[k], z[k]));
  }
}

// K2: zero d_out (fused fill) + count hits for 4 rows (one wave per row)
__global__ __launch_bounds__(256) void nl_count_fill(const float* __restrict__ pos,
                                                     float* __restrict__ out,
                                                     float* __restrict__ ws) {
  float4* o4 = (float4*)out;
  const int b = blockIdx.x;
  o4[b * 512 + threadIdx.x] = make_float4(0.f, 0.f, 0.f, 0.f);
  o4[b * 512 + 256 + threadIdx.x] = make_float4(0.f, 0.f, 0.f, 0.f);

  const int* celloff = (const int*)(ws + W_CELLOFF);
  const int* sortid = (const int*)(ws + W_SORTID);
  const float4* sortpos = (const float4*)(ws + W_SORTPOS);
  int* rowcnt = (int*)(ws + W_ROWCNT);
  const int lane = threadIdx.x & 63;
  const int wave = threadIdx.x >> 6;
  const int row = b * 4 + wave;
  float xi = pos[3 * row], yi = pos[3 * row + 1], zi = pos[3 * row + 2];
  float sqi = sq3_nc(xi, yi, zi);
  int cx = cellco(xi), cy = cellco(yi), cz = cellco(zi);
  int x0 = max(cx - 1, 0), x1 = min(cx + 1, 6);
  int y0 = max(cy - 1, 0), y1 = min(cy + 1, 6);
  int z0 = max(cz - 1, 0), z1 = min(cz + 1, 6);
  int cnt = 0;
  for (int icz = z0; icz <= z1; ++icz)
    for (int icy = y0; icy <= y1; ++icy) {
      int cb = 7 * icy + 49 * icz;
      int s = celloff[cb + x0];
      int e = celloff[cb + x1 + 1];
      for (int bb = s; bb < e; bb += 64) {
        int t = bb + lane;
        bool v = t < e;
        float4 p = v ? sortpos[t] : make_float4(1e30f, 1e30f, 1e30f, 0.f);
        int j = v ? sortid[t] : -1;
        float d2 = d2_gram(xi, yi, zi, sqi, p.x, p.y, p.z, p.w);
        cnt += (v && (d2 < D2_CUT) && (j != row)) ? 1 : 0;
      }
    }
  for (int off = 32; off > 0; off >>= 1) cnt += __shfl_down(cnt, off, 64);
  if (lane == 0) rowcnt[row] = cnt;
}

// K3: self-scan row offsets (block-local, redundant) + collect + rank-sort + write
__global__ __launch_bounds__(256) void nl_write(const float* __restrict__ pos,
                                                float* __restrict__ out,
                                                const float* __restrict__ ws) {
  const int* celloff = (const int*)(ws + W_CELLOFF);
  const int* sortid = (const int*)(ws + W_SORTID);
  const float4* sortpos = (const float4*)(ws + W_SORTPOS);
  const int* rowcnt = (const int*)(ws + W_ROWCNT);
  __shared__ int pfx[NATOMS];   // 32 KB: per-row exclusive prefix (within thread chunk)
  __shared__ int tsum[256];     // thread-chunk sums -> inclusive block scan
  __shared__ int jb[4][CAP];
  __shared__ float db[4][CAP];
  const int tid = threadIdx.x;
  const int lane = tid & 63;
  const int wave = tid >> 6;
  const int row = blockIdx.x * 4 + wave;

  int run = 0;
  for (int k = 0; k < 32; ++k) {
    pfx[tid * 32 + k] = run;
    run += rowcnt[tid * 32 + k];
  }
  tsum[tid] = run;
  __syncthreads();
  for (int off = 1; off < 256; off <<= 1) {
    int v = (tid >= off) ? tsum[tid - off] : 0;
    __syncthreads();
    tsum[tid] += v;
    __syncthreads();
  }

  float xi = pos[3 * row], yi = pos[3 * row + 1], zi = pos[3 * row + 2];
  float sqi = sq3_nc(xi, yi, zi);
  int cx = cellco(xi), cy = cellco(yi), cz = cellco(zi);
  int x0 = max(cx - 1, 0), x1 = min(cx + 1, 6);
  int y0 = max(cy - 1, 0), y1 = min(cy + 1, 6);
  int z0 = max(cz - 1, 0), z1 = min(cz + 1, 6);
  int cnt = 0;
  for (int icz = z0; icz <= z1; ++icz)
    for (int icy = y0; icy <= y1; ++icy) {
      int cb = 7 * icy + 49 * icz;
      int s = celloff[cb + x0];
      int e = celloff[cb + x1 + 1];
      for (int bb = s; bb < e; bb += 64) {
        int t = bb + lane;
        bool v = t < e;
        float4 p = v ? sortpos[t] : make_float4(1e30f, 1e30f, 1e30f, 0.f);
        int j = v ? sortid[t] : -1;
        float d2 = d2_gram(xi, yi, zi, sqi, p.x, p.y, p.z, p.w);
        bool pred = v && (d2 < D2_CUT) && (j != row);
        unsigned long long m = __ballot(pred ? 1 : 0);
        if (pred) {
          int ps = cnt + __popcll(m & ((1ull << lane) - 1ull));
          if (ps < CAP) {
            jb[wave][ps] = j;
            db[wave][ps] = sqrtf(d2_direct(xi, yi, zi, p.x, p.y, p.z));
          }
        }
        cnt += __popcll(m);
      }
    }
  __syncthreads();

  int k = cnt > CAP ? CAP : cnt;
  int base = pfx[row] + ((row >= 32) ? tsum[(row >> 5) - 1] : 0);
  for (int midx = lane; midx < k; midx += 64) {
    int jm = jb[wave][midx];
    int rank = 0;
    for (int t = 0; t < k; ++t) rank += (jb[wave][t] < jm) ? 1 : 0;
    int idx = base + rank;
    if (idx < MAXP) {
      ((float2*)out)[idx] = make_float2((float)row, (float)jm);  // interleaved pair
      out[2 * MAXP + idx] = (row < jm) ? 1.0f : 0.0f;            // buffer_scales
      out[3 * MAXP + idx] = db[wave][midx];                      // ds
    }
  }
}

extern "C" void kernel_launch(void* const* d_in, const int* in_sizes, int n_in,
                              void* d_out, int out_size, void* d_ws, size_t ws_size,
                              hipStream_t stream) {
  const float* pos = (const float*)d_in[0];  // float32 [8192,3]
  float* out = (float*)d_out;                // float32 [4*MAXP]
  float* ws = (float*)d_ws;

  nl_bin<<<1, 1024, 0, stream>>>(pos, ws);
  nl_count_fill<<<2048, 256, 0, stream>>>(pos, out, ws);
  nl_write<<<2048, 256, 0, stream>>>(pos, out, ws);
}